// Round 3
// baseline (221.427 us; speedup 1.0000x reference)
//
#include <hip/hip_runtime.h>
#include <stdint.h>

#define N_Q   65536
#define N_S   65536
#define NB_H  26
#define PAD_H 28
#define KP    10
#define CIN   64
#define COUT  128
#define MT    16   // query points per block

typedef unsigned short u16x4  __attribute__((ext_vector_type(4)));
typedef unsigned short u16x8  __attribute__((ext_vector_type(8)));
typedef float          f32x4  __attribute__((ext_vector_type(4)));
typedef __bf16         bf16x8 __attribute__((ext_vector_type(8)));

#define CVT_BLOCKS 2049   // ceil((N_S+1)*CIN/8 / 256)
#define PACK_BLOCKS 40    // ceil(8*20*64 / 256)

static __device__ __forceinline__ unsigned short f2bf(float f) {
  unsigned int u = __float_as_uint(f);
  u += 0x7fffu + ((u >> 16) & 1u);          // round-to-nearest-even
  return (unsigned short)(u >> 16);
}
static __device__ __forceinline__ float bf2f(unsigned short h) {
  return __uint_as_float(((unsigned int)h) << 16);
}

// ---- prep: x fp32 -> bf16 (+ zero shadow row) AND weight pack, one launch ---
// Bpack[((ct*20 + ks)*64 + lane)*8 + j] = B[ks*32 + (lane>>4)*8 + j][ct*16 + (lane&15)]
__global__ void prep_kernel(const float* __restrict__ x,
                            const float* __restrict__ w,
                            unsigned short* __restrict__ xb,
                            unsigned short* __restrict__ bp) {
  if (blockIdx.x < CVT_BLOCKS) {
    long t = (long)blockIdx.x * blockDim.x + threadIdx.x;   // one thread per 8 elems
    long off = t * 8;
    if (off >= (long)(N_S + 1) * CIN) return;
    u16x8 o;
    if (off < (long)N_S * CIN) {
      f32x4 a = *(const f32x4*)(x + off);
      f32x4 b = *(const f32x4*)(x + off + 4);
      o[0] = f2bf(a[0]); o[1] = f2bf(a[1]); o[2] = f2bf(a[2]); o[3] = f2bf(a[3]);
      o[4] = f2bf(b[0]); o[5] = f2bf(b[1]); o[6] = f2bf(b[2]); o[7] = f2bf(b[3]);
    } else {
      o = (u16x8)0;                       // shadow feature row = zeros
    }
    *(u16x8*)(xb + off) = o;
  } else {
    int t = (blockIdx.x - CVT_BLOCKS) * blockDim.x + threadIdx.x;
    if (t >= 8 * 20 * 64) return;
    int lane = t & 63;
    int frag = t >> 6;            // ct*20 + ks
    int ks = frag % 20;
    int ct = frag / 20;
    int row0 = ks * 32 + (lane >> 4) * 8;
    int col  = ct * 16 + (lane & 15);
    u16x8 o;
    #pragma unroll
    for (int j = 0; j < 8; ++j) o[j] = f2bf(w[(row0 + j) * COUT + col]);
    *(u16x8*)(bp + (long)t * 8) = o;
  }
}

// ---- main fused kernel ------------------------------------------------------
// LDS: sh_ind 1664 + sh_aw 16640 + pool 20736 = 39040 B -> 4 blocks/CU
__global__ void __launch_bounds__(256, 4)
kpconv_main(const float* __restrict__ q_pts, const float* __restrict__ s_pts,
            const float* __restrict__ gen_W, const float* __restrict__ gen_b,
            const int* __restrict__ inds, const unsigned short* __restrict__ xb,
            const unsigned short* __restrict__ bp, float* __restrict__ out) {

  __shared__ int   sh_ind[MT][NB_H];              //  1664 B
  // sh_aw layout: [m][h][k] (h-major -> 10 contiguous k per h, ds_read_b64 x5)
  // m-stride 260 words % 32 == 4 -> the 4 broadcast addrs/wave hit distinct banks
  __shared__ float sh_aw[MT][NB_H * KP];          // 16640 B
  __shared__ __align__(16) char pool[MT * 648 * 2];  // 20736 B

  // overlapping views: nbr/kp are dead before sh_w is written (barrier between)
  float* sh_nbr = (float*)pool;                      // [MT][NB_H][3] = 4992 B
  float* sh_kp  = (float*)(pool + MT * NB_H * 3 * 4);// [MT][KP*3]   = 1920 B
  unsigned short* sh_w = (unsigned short*)pool;      // [MT][648]    = 20736 B

  const int tid  = threadIdx.x;
  const int base = blockIdx.x * MT;

  // ---- Phase A: neighbors = s_pad[ind] - q ----
  for (int p = tid; p < MT * NB_H; p += 256) {
    int m = p / NB_H, h = p % NB_H;
    int n = base + m;
    int ind = inds[n * NB_H + h];
    sh_ind[m][h] = ind;
    float sx, sy, sz;
    if ((unsigned)ind < (unsigned)N_S) {
      sx = s_pts[ind * 3 + 0]; sy = s_pts[ind * 3 + 1]; sz = s_pts[ind * 3 + 2];
    } else {
      sx = 1e6f; sy = 1e6f; sz = 1e6f;   // shadow support point
    }
    sh_nbr[(m * NB_H + h) * 3 + 0] = sx - q_pts[n * 3 + 0];
    sh_nbr[(m * NB_H + h) * 3 + 1] = sy - q_pts[n * 3 + 1];
    sh_nbr[(m * NB_H + h) * 3 + 2] = sz - q_pts[n * 3 + 2];
  }
  __syncthreads();

  // ---- Phase A2: kernel points kp = padded @ gen_W^T + gen_b ----
  // padding slots (H..PAD_H) are constant -1 -> folded into bias.
  for (int p = tid; p < MT * KP * 3; p += 256) {
    int m = p / (KP * 3), r = p % (KP * 3);
    const float* Wr = gen_W + r * (PAD_H * 3);
    float acc = gen_b[r];
    #pragma unroll
    for (int c = NB_H * 3; c < PAD_H * 3; ++c) acc -= Wr[c];
    for (int h = 0; h < NB_H; ++h) {
      acc += Wr[h * 3 + 0] * sh_nbr[(m * NB_H + h) * 3 + 0]
           + Wr[h * 3 + 1] * sh_nbr[(m * NB_H + h) * 3 + 1]
           + Wr[h * 3 + 2] * sh_nbr[(m * NB_H + h) * 3 + 2];
    }
    sh_kp[m * KP * 3 + r] = acc;
  }
  __syncthreads();

  // ---- Phase B: all_w[m][h][k] = max(1 - |nbr - kp| / 1.2, 0) (fp32) ----
  for (int p = tid; p < MT * KP * NB_H; p += 256) {
    int m = p / (KP * NB_H);
    int r = p - m * (KP * NB_H);
    int k = r / NB_H, h = r % NB_H;
    float dx = sh_nbr[(m * NB_H + h) * 3 + 0] - sh_kp[m * KP * 3 + k * 3 + 0];
    float dy = sh_nbr[(m * NB_H + h) * 3 + 1] - sh_kp[m * KP * 3 + k * 3 + 1];
    float dz = sh_nbr[(m * NB_H + h) * 3 + 2] - sh_kp[m * KP * 3 + k * 3 + 2];
    float d  = sqrtf(dx * dx + dy * dy + dz * dz);
    sh_aw[m][h * KP + k] = fmaxf(1.0f - d * (1.0f / 1.2f), 0.0f);
  }
  __syncthreads();

  // ---- Phase C: weighted[m][k][i] = sum_h all_w[m][h][k] * x[ind[m][h]][i] ----
  // 16 threads per point, 4 channels each; 13-deep rotating register prefetch.
  {
    const int m  = tid >> 4;
    const int i0 = (tid & 15) * 4;
    float acc[KP][4];
    #pragma unroll
    for (int k = 0; k < KP; ++k)
      #pragma unroll
      for (int j = 0; j < 4; ++j) acc[k][j] = 0.0f;

    u16x4 xr[13];
    #pragma unroll
    for (int h = 0; h < 13; ++h)
      xr[h] = *(const u16x4*)(xb + (long)sh_ind[m][h] * CIN + i0);

    // first half: consume row h, immediately refill slot with row h+13
    #pragma unroll
    for (int h = 0; h < 13; ++h) {
      u16x4 xc = xr[h];
      xr[h] = *(const u16x4*)(xb + (long)sh_ind[m][h + 13] * CIN + i0);
      float xf0 = bf2f(xc[0]), xf1 = bf2f(xc[1]);
      float xf2 = bf2f(xc[2]), xf3 = bf2f(xc[3]);
      const float* wrow = &sh_aw[m][h * KP];
      #pragma unroll
      for (int k = 0; k < KP; ++k) {
        float w = wrow[k];
        acc[k][0] = fmaf(w, xf0, acc[k][0]);
        acc[k][1] = fmaf(w, xf1, acc[k][1]);
        acc[k][2] = fmaf(w, xf2, acc[k][2]);
        acc[k][3] = fmaf(w, xf3, acc[k][3]);
      }
    }
    // second half
    #pragma unroll
    for (int h = 0; h < 13; ++h) {
      u16x4 xc = xr[h];
      float xf0 = bf2f(xc[0]), xf1 = bf2f(xc[1]);
      float xf2 = bf2f(xc[2]), xf3 = bf2f(xc[3]);
      const float* wrow = &sh_aw[m][(h + 13) * KP];
      #pragma unroll
      for (int k = 0; k < KP; ++k) {
        float w = wrow[k];
        acc[k][0] = fmaf(w, xf0, acc[k][0]);
        acc[k][1] = fmaf(w, xf1, acc[k][1]);
        acc[k][2] = fmaf(w, xf2, acc[k][2]);
        acc[k][3] = fmaf(w, xf3, acc[k][3]);
      }
    }
    __syncthreads();   // nbr/kp fully consumed; pool may now become sh_w
    #pragma unroll
    for (int k = 0; k < KP; ++k) {
      u16x4 o;
      #pragma unroll
      for (int j = 0; j < 4; ++j) o[j] = f2bf(acc[k][j]);
      *(u16x4*)&sh_w[m * 648 + k * CIN + i0] = o;
    }
  }
  __syncthreads();

  // ---- Phase D: out[16][128] = weighted[16][640] @ B[640][128] via MFMA ----
  {
    const int wave = tid >> 6;
    const int lane = tid & 63;
    const int arow = lane & 15;
    const int ak   = (lane >> 4) * 8;
    const int ct0  = wave * 2, ct1 = ct0 + 1;
    f32x4 acc0 = {0.f, 0.f, 0.f, 0.f}, acc1 = {0.f, 0.f, 0.f, 0.f};
    for (int ks = 0; ks < 20; ++ks) {
      u16x8 au  = *(const u16x8*)&sh_w[arow * 648 + ks * 32 + ak];
      u16x8 b0u = *(const u16x8*)(bp + (long)((ct0 * 20 + ks) * 64 + lane) * 8);
      u16x8 b1u = *(const u16x8*)(bp + (long)((ct1 * 20 + ks) * 64 + lane) * 8);
      bf16x8 a  = __builtin_bit_cast(bf16x8, au);
      bf16x8 b0 = __builtin_bit_cast(bf16x8, b0u);
      bf16x8 b1 = __builtin_bit_cast(bf16x8, b1u);
      acc0 = __builtin_amdgcn_mfma_f32_16x16x32_bf16(a, b0, acc0, 0, 0, 0);
      acc1 = __builtin_amdgcn_mfma_f32_16x16x32_bf16(a, b1, acc1, 0, 0, 0);
    }
    // C/D layout: col = lane&15, row = (lane>>4)*4 + reg  [measured m89/m91]
    const int col   = lane & 15;
    const int rbase = (lane >> 4) * 4;
    #pragma unroll
    for (int r = 0; r < 4; ++r) {
      out[(long)(base + rbase + r) * COUT + ct0 * 16 + col] = acc0[r];
      out[(long)(base + rbase + r) * COUT + ct1 * 16 + col] = acc1[r];
    }
  }
}

extern "C" void kernel_launch(void* const* d_in, const int* in_sizes, int n_in,
                              void* d_out, int out_size, void* d_ws, size_t ws_size,
                              hipStream_t stream) {
  const float* q_pts = (const float*)d_in[0];
  const float* s_pts = (const float*)d_in[1];
  const float* x     = (const float*)d_in[2];
  const float* gen_W = (const float*)d_in[3];
  const float* gen_b = (const float*)d_in[4];
  const float* wts   = (const float*)d_in[5];
  const int*   inds  = (const int*)d_in[6];
  float* out = (float*)d_out;

  unsigned short* xb = (unsigned short*)d_ws;            // (N_S+1)*CIN bf16
  unsigned short* bp = xb + (size_t)(N_S + 1) * CIN;     // 81920 bf16 = 160 KiB

  prep_kernel<<<CVT_BLOCKS + PACK_BLOCKS, 256, 0, stream>>>(x, wts, xb, bp);
  kpconv_main<<<N_Q / MT, 256, 0, stream>>>(q_pts, s_pts, gen_W, gen_b,
                                            inds, xb, bp, out);
}

// Round 4
// 189.890 us; speedup vs baseline: 1.1661x; 1.1661x over previous
//
#include <hip/hip_runtime.h>
#include <stdint.h>

#define N_Q   65536
#define N_S   65536
#define NB_H  26
#define PAD_H 28
#define KP    10
#define CIN   64
#define COUT  128
#define MT    16   // query points per gather block
#define BM    64   // gemm row tile

typedef unsigned short u16x4  __attribute__((ext_vector_type(4)));
typedef unsigned short u16x8  __attribute__((ext_vector_type(8)));
typedef float          f32x4  __attribute__((ext_vector_type(4)));
typedef __bf16         bf16x8 __attribute__((ext_vector_type(8)));

#define CVT_BLOCKS 2049   // ceil((N_S+1)*CIN/8 / 256)
#define PACK_BLOCKS 40    // ceil(8*20*64 / 256)

static __device__ __forceinline__ unsigned short f2bf(float f) {
  unsigned int u = __float_as_uint(f);
  u += 0x7fffu + ((u >> 16) & 1u);          // round-to-nearest-even
  return (unsigned short)(u >> 16);
}
static __device__ __forceinline__ float bf2f(unsigned short h) {
  return __uint_as_float(((unsigned int)h) << 16);
}

// ---- prep: x fp32 -> bf16 (+ zero shadow row) AND weight pack, one launch ---
// Bpack[((ct*20 + ks)*64 + lane)*8 + j] = B[ks*32 + (lane>>4)*8 + j][ct*16 + (lane&15)]
__global__ void prep_kernel(const float* __restrict__ x,
                            const float* __restrict__ w,
                            unsigned short* __restrict__ xb,
                            unsigned short* __restrict__ bp) {
  if (blockIdx.x < CVT_BLOCKS) {
    long t = (long)blockIdx.x * blockDim.x + threadIdx.x;
    long off = t * 8;
    if (off >= (long)(N_S + 1) * CIN) return;
    u16x8 o;
    if (off < (long)N_S * CIN) {
      f32x4 a = *(const f32x4*)(x + off);
      f32x4 b = *(const f32x4*)(x + off + 4);
      o[0] = f2bf(a[0]); o[1] = f2bf(a[1]); o[2] = f2bf(a[2]); o[3] = f2bf(a[3]);
      o[4] = f2bf(b[0]); o[5] = f2bf(b[1]); o[6] = f2bf(b[2]); o[7] = f2bf(b[3]);
    } else {
      o = (u16x8)0;                       // shadow feature row = zeros
    }
    *(u16x8*)(xb + off) = o;
  } else {
    int t = (blockIdx.x - CVT_BLOCKS) * blockDim.x + threadIdx.x;
    if (t >= 8 * 20 * 64) return;
    int lane = t & 63;
    int frag = t >> 6;            // ct*20 + ks
    int ks = frag % 20;
    int ct = frag / 20;
    int row0 = ks * 32 + (lane >> 4) * 8;
    int col  = ct * 16 + (lane & 15);
    u16x8 o;
    #pragma unroll
    for (int j = 0; j < 8; ++j) o[j] = f2bf(w[(row0 + j) * COUT + col]);
    *(u16x8*)(bp + (long)t * 8) = o;
  }
}

// ---- kernel A: phases A,A2,B,C -> weighted[N][640] bf16 ---------------------
// LDS: 1664 + 4992 + 1920 + 16640 = 25216 B -> 6 blocks/CU (24 waves, 75% occ)
// VGPR budget: acc 40 + prefetch 10 + misc ~8 = ~58, under the 64-reg cliff
// (round-3 lesson: allocator spills rather than exceed 64 here).
__global__ void __launch_bounds__(256, 4)
kpconv_gather(const float* __restrict__ q_pts, const float* __restrict__ s_pts,
              const float* __restrict__ gen_W, const float* __restrict__ gen_b,
              const int* __restrict__ inds, const unsigned short* __restrict__ xb,
              unsigned short* __restrict__ wg) {

  __shared__ int   sh_ind[MT][NB_H];              //  1664 B
  __shared__ float sh_nbr[MT][NB_H][3];           //  4992 B
  __shared__ float sh_kp[MT][KP * 3];             //  1920 B
  // [m][h][k]: 10 contiguous k per h -> ds_read_b64 x5; m-stride 260 % 32 = 4
  __shared__ float sh_aw[MT][NB_H * KP];          // 16640 B

  const int tid  = threadIdx.x;
  const int base = blockIdx.x * MT;

  // ---- Phase A: neighbors = s_pad[ind] - q ----
  for (int p = tid; p < MT * NB_H; p += 256) {
    int m = p / NB_H, h = p % NB_H;
    int n = base + m;
    int ind = inds[n * NB_H + h];
    sh_ind[m][h] = ind;
    float sx, sy, sz;
    if ((unsigned)ind < (unsigned)N_S) {
      sx = s_pts[ind * 3 + 0]; sy = s_pts[ind * 3 + 1]; sz = s_pts[ind * 3 + 2];
    } else {
      sx = 1e6f; sy = 1e6f; sz = 1e6f;   // shadow support point
    }
    sh_nbr[m][h][0] = sx - q_pts[n * 3 + 0];
    sh_nbr[m][h][1] = sy - q_pts[n * 3 + 1];
    sh_nbr[m][h][2] = sz - q_pts[n * 3 + 2];
  }
  __syncthreads();

  // ---- Phase A2: kernel points kp = padded @ gen_W^T + gen_b ----
  // padding slots (H..PAD_H) are constant -1 -> folded into bias.
  for (int p = tid; p < MT * KP * 3; p += 256) {
    int m = p / (KP * 3), r = p % (KP * 3);
    const float* Wr = gen_W + r * (PAD_H * 3);
    float acc = gen_b[r];
    #pragma unroll
    for (int c = NB_H * 3; c < PAD_H * 3; ++c) acc -= Wr[c];
    for (int h = 0; h < NB_H; ++h) {
      acc += Wr[h * 3 + 0] * sh_nbr[m][h][0]
           + Wr[h * 3 + 1] * sh_nbr[m][h][1]
           + Wr[h * 3 + 2] * sh_nbr[m][h][2];
    }
    sh_kp[m][r] = acc;
  }
  __syncthreads();

  // ---- Phase B: all_w[m][h][k] = max(1 - |nbr - kp| / 1.2, 0) ----
  for (int p = tid; p < MT * KP * NB_H; p += 256) {
    int m = p / (KP * NB_H);
    int r = p - m * (KP * NB_H);
    int k = r / NB_H, h = r % NB_H;
    float dx = sh_nbr[m][h][0] - sh_kp[m][k * 3 + 0];
    float dy = sh_nbr[m][h][1] - sh_kp[m][k * 3 + 1];
    float dz = sh_nbr[m][h][2] - sh_kp[m][k * 3 + 2];
    float d  = sqrtf(dx * dx + dy * dy + dz * dz);
    sh_aw[m][h * KP + k] = fmaxf(1.0f - d * (1.0f / 1.2f), 0.0f);
  }
  __syncthreads();

  // ---- Phase C: weighted[m][k][i] = sum_h all_w[m][h][k] * x[ind[m][h]][i] ----
  // 16 threads per point, 4 channels each; depth-5 rotating register prefetch.
  {
    const int m  = tid >> 4;
    const int i0 = (tid & 15) * 4;
    float acc[KP][4];
    #pragma unroll
    for (int k = 0; k < KP; ++k)
      #pragma unroll
      for (int j = 0; j < 4; ++j) acc[k][j] = 0.0f;

    u16x4 xr[5];
    #pragma unroll
    for (int h = 0; h < 5; ++h)
      xr[h] = *(const u16x4*)(xb + (long)sh_ind[m][h] * CIN + i0);

    #pragma unroll
    for (int h = 0; h < NB_H; ++h) {
      u16x4 xc = xr[h % 5];
      if (h + 5 < NB_H)
        xr[h % 5] = *(const u16x4*)(xb + (long)sh_ind[m][h + 5] * CIN + i0);
      float xf0 = bf2f(xc[0]), xf1 = bf2f(xc[1]);
      float xf2 = bf2f(xc[2]), xf3 = bf2f(xc[3]);
      const float* wrow = &sh_aw[m][h * KP];
      #pragma unroll
      for (int k = 0; k < KP; ++k) {
        float w = wrow[k];
        acc[k][0] = fmaf(w, xf0, acc[k][0]);
        acc[k][1] = fmaf(w, xf1, acc[k][1]);
        acc[k][2] = fmaf(w, xf2, acc[k][2]);
        acc[k][3] = fmaf(w, xf3, acc[k][3]);
      }
    }
    #pragma unroll
    for (int k = 0; k < KP; ++k) {
      u16x4 o;
      #pragma unroll
      for (int j = 0; j < 4; ++j) o[j] = f2bf(acc[k][j]);
      *(u16x4*)(wg + (long)(base + m) * (KP * CIN) + k * CIN + i0) = o;
    }
  }
}

// ---- kernel B: out[65536][128] = wg[65536][640] @ B[640][128] (MFMA) --------
// BM=64 rows/block, 4 waves x 2 col-tiles, BK=64 double-buffered LDS A-chunks.
// A-chunk stride 72 shorts (144 B) -> even bank tiling for b128 reads/writes.
__global__ void __launch_bounds__(256, 4)
kpconv_gemm(const unsigned short* __restrict__ wg,
            const unsigned short* __restrict__ bp,
            float* __restrict__ out) {

  __shared__ unsigned short sA[2][BM][72];   // 2 x 9216 B

  const int tid  = threadIdx.x;
  const int wave = tid >> 6;
  const int lane = tid & 63;
  const long row0 = (long)blockIdx.x * BM;

  const int srow = tid >> 3;        // 0..31
  const int scb  = tid & 7;         // col block 0..7

  // stage chunk 0
  {
    u16x8 a = *(const u16x8*)(wg + (row0 + srow) * 640 + scb * 8);
    u16x8 b = *(const u16x8*)(wg + (row0 + srow + 32) * 640 + scb * 8);
    *(u16x8*)&sA[0][srow][scb * 8] = a;
    *(u16x8*)&sA[0][srow + 32][scb * 8] = b;
  }

  f32x4 acc[4][2];
  #pragma unroll
  for (int rt = 0; rt < 4; ++rt)
    #pragma unroll
    for (int c = 0; c < 2; ++c) acc[rt][c] = (f32x4){0.f, 0.f, 0.f, 0.f};

  const int ct0  = wave * 2, ct1 = ct0 + 1;
  const int arow = lane & 15;
  const int aq   = lane >> 4;
  int cur = 0;

  for (int kc = 0; kc < 10; ++kc) {
    __syncthreads();
    u16x8 p0, p1;
    if (kc < 9) {   // prefetch next A-chunk (HBM), hidden behind MFMA phase
      p0 = *(const u16x8*)(wg + (row0 + srow) * 640 + (kc + 1) * 64 + scb * 8);
      p1 = *(const u16x8*)(wg + (row0 + srow + 32) * 640 + (kc + 1) * 64 + scb * 8);
    }
    #pragma unroll
    for (int ks2 = 0; ks2 < 2; ++ks2) {
      int ks = kc * 2 + ks2;
      u16x8 b0u = *(const u16x8*)(bp + (long)((ct0 * 20 + ks) * 64 + lane) * 8);
      u16x8 b1u = *(const u16x8*)(bp + (long)((ct1 * 20 + ks) * 64 + lane) * 8);
      bf16x8 b0 = __builtin_bit_cast(bf16x8, b0u);
      bf16x8 b1 = __builtin_bit_cast(bf16x8, b1u);
      #pragma unroll
      for (int rt = 0; rt < 4; ++rt) {
        u16x8 au = *(const u16x8*)&sA[cur][rt * 16 + arow][ks2 * 32 + aq * 8];
        bf16x8 a = __builtin_bit_cast(bf16x8, au);
        acc[rt][0] = __builtin_amdgcn_mfma_f32_16x16x32_bf16(a, b0, acc[rt][0], 0, 0, 0);
        acc[rt][1] = __builtin_amdgcn_mfma_f32_16x16x32_bf16(a, b1, acc[rt][1], 0, 0, 0);
      }
    }
    if (kc < 9) {
      *(u16x8*)&sA[1 - cur][srow][scb * 8] = p0;
      *(u16x8*)&sA[1 - cur][srow + 32][scb * 8] = p1;
      cur ^= 1;
    }
  }

  // C/D layout: col = lane&15, row = (lane>>4)*4 + reg  [measured m89/m91]
  const int col   = lane & 15;
  const int rbase = aq * 4;
  #pragma unroll
  for (int rt = 0; rt < 4; ++rt)
    #pragma unroll
    for (int r = 0; r < 4; ++r) {
      long row = row0 + rt * 16 + rbase + r;
      out[row * COUT + ct0 * 16 + col] = acc[rt][0][r];
      out[row * COUT + ct1 * 16 + col] = acc[rt][1][r];
    }
}

extern "C" void kernel_launch(void* const* d_in, const int* in_sizes, int n_in,
                              void* d_out, int out_size, void* d_ws, size_t ws_size,
                              hipStream_t stream) {
  const float* q_pts = (const float*)d_in[0];
  const float* s_pts = (const float*)d_in[1];
  const float* x     = (const float*)d_in[2];
  const float* gen_W = (const float*)d_in[3];
  const float* gen_b = (const float*)d_in[4];
  const float* wts   = (const float*)d_in[5];
  const int*   inds  = (const int*)d_in[6];
  float* out = (float*)d_out;

  unsigned short* xb = (unsigned short*)d_ws;            // (N_S+1)*CIN bf16 = 8.39 MB
  unsigned short* bp = xb + (size_t)(N_S + 1) * CIN;     // 81920 bf16 = 160 KB
  unsigned short* wg = bp + (size_t)81920;               // N_Q*640 bf16 = 83.9 MB

  prep_kernel<<<CVT_BLOCKS + PACK_BLOCKS, 256, 0, stream>>>(x, wts, xb, bp);
  kpconv_gather<<<N_Q / MT, 256, 0, stream>>>(q_pts, s_pts, gen_W, gen_b,
                                              inds, xb, wg);
  kpconv_gemm<<<N_Q / BM, 256, 0, stream>>>(wg, bp, out);
}

// Round 6
// 174.343 us; speedup vs baseline: 1.2701x; 1.0892x over previous
//
#include <hip/hip_runtime.h>
#include <stdint.h>

#define N_Q   65536
#define N_S   65536
#define NB_H  26
#define PAD_H 28
#define KP    10
#define CIN   64
#define COUT  128
#define MT    8    // query points per gather block
#define BM    64   // gemm row tile

typedef unsigned short u16x4  __attribute__((ext_vector_type(4)));
typedef unsigned short u16x8  __attribute__((ext_vector_type(8)));
typedef float          f32x4  __attribute__((ext_vector_type(4)));
typedef _Float16       f16x8  __attribute__((ext_vector_type(8)));
typedef _Float16       f16x2  __attribute__((ext_vector_type(2)));

#define CVT_BLOCKS 2049   // ceil((N_S+1)*CIN/8 / 256)
#define PACK_BLOCKS 40    // ceil(8*20*64 / 256)

static __device__ __forceinline__ unsigned short f2h(float f) {
  return __builtin_bit_cast(unsigned short, (_Float16)f);
}

// v_cvt_pkrtz_f16_f32 packed to raw u32 (builtin returns __fp16x2, not _Float16x2)
static __device__ __forceinline__ unsigned int pkrtz_u32(float a, float b) {
  return __builtin_bit_cast(unsigned int, __builtin_amdgcn_cvt_pkrtz(a, b));
}

// half2-dot with fp32 accumulate: v_dot2_f32_f16 (2 MACs/lane/instr, 2x fp32 rate)
static __device__ __forceinline__ float fdot2u(unsigned int a, unsigned int b, float c) {
#if __has_builtin(__builtin_amdgcn_fdot2)
  return __builtin_amdgcn_fdot2(__builtin_bit_cast(f16x2, a),
                                __builtin_bit_cast(f16x2, b), c, false);
#else
  f16x2 ha = __builtin_bit_cast(f16x2, a), hb = __builtin_bit_cast(f16x2, b);
  return c + (float)ha[0] * (float)hb[0] + (float)ha[1] * (float)hb[1];
#endif
}

// ---- prep: x fp32 -> fp16 (+ zero shadow row) AND weight pack (fp16) --------
// Bpack[((ct*20 + ks)*64 + lane)*8 + j] = B[ks*32 + (lane>>4)*8 + j][ct*16 + (lane&15)]
__global__ void prep_kernel(const float* __restrict__ x,
                            const float* __restrict__ w,
                            unsigned short* __restrict__ xh,
                            unsigned short* __restrict__ bp) {
  if (blockIdx.x < CVT_BLOCKS) {
    long t = (long)blockIdx.x * blockDim.x + threadIdx.x;
    long off = t * 8;
    if (off >= (long)(N_S + 1) * CIN) return;
    u16x8 o;
    if (off < (long)N_S * CIN) {
      f32x4 a = *(const f32x4*)(x + off);
      f32x4 b = *(const f32x4*)(x + off + 4);
      o[0] = f2h(a[0]); o[1] = f2h(a[1]); o[2] = f2h(a[2]); o[3] = f2h(a[3]);
      o[4] = f2h(b[0]); o[5] = f2h(b[1]); o[6] = f2h(b[2]); o[7] = f2h(b[3]);
    } else {
      o = (u16x8)0;                       // shadow feature row = zeros
    }
    *(u16x8*)(xh + off) = o;
  } else {
    int t = (blockIdx.x - CVT_BLOCKS) * blockDim.x + threadIdx.x;
    if (t >= 8 * 20 * 64) return;
    int lane = t & 63;
    int frag = t >> 6;            // ct*20 + ks
    int ks = frag % 20;
    int ct = frag / 20;
    int row0 = ks * 32 + (lane >> 4) * 8;
    int col  = ct * 16 + (lane & 15);
    u16x8 o;
    #pragma unroll
    for (int j = 0; j < 8; ++j) o[j] = f2h(w[(row0 + j) * COUT + col]);
    *(u16x8*)(bp + (long)t * 8) = o;
  }
}

// ---- kernel A: phases A,A2,B,C -> weighted[N][640] fp16 ---------------------
// LDS: 832 + 2560 + 960 + 4992 = 9344 B. VGPR live peak ~50 (acc 20 + xr 4 +
// misc) -> no spill at the (256,6) 85-reg budget (round-3 lesson: watch 64 cliff).
__global__ void __launch_bounds__(256, 6)
kpconv_gather(const float* __restrict__ q_pts, const float* __restrict__ s_pts,
              const float* __restrict__ gen_W, const float* __restrict__ gen_b,
              const int* __restrict__ inds, const unsigned short* __restrict__ xh,
              unsigned short* __restrict__ wg) {

  __shared__ int          sh_ind[MT][NB_H];        //  832 B
  __shared__ float        sh_nbr[MT][80];          // 2560 B (78 used + 2 pad=-1; 16B-aligned rows)
  __shared__ float        sh_kp[MT][KP * 3];       //  960 B
  __shared__ unsigned int sh_aw[MT][13][12];       // 4992 B: half2 (w[h0],w[h1]) per (hp,k), pad 10->12

  const int tid  = threadIdx.x;
  const int base = blockIdx.x * MT;

  // ---- Phase A: neighbors = s_pad[ind] - q; pad channels 78,79 = -1 ----
  if (tid < MT * NB_H) {
    int m = tid / NB_H, h = tid % NB_H;
    int n = base + m;
    int ind = inds[n * NB_H + h];
    sh_ind[m][h] = ind;
    float sx, sy, sz;
    if ((unsigned)ind < (unsigned)N_S) {
      sx = s_pts[ind * 3 + 0]; sy = s_pts[ind * 3 + 1]; sz = s_pts[ind * 3 + 2];
    } else {
      sx = 1e6f; sy = 1e6f; sz = 1e6f;   // shadow support point
    }
    sh_nbr[m][h * 3 + 0] = sx - q_pts[n * 3 + 0];
    sh_nbr[m][h * 3 + 1] = sy - q_pts[n * 3 + 1];
    sh_nbr[m][h * 3 + 2] = sz - q_pts[n * 3 + 2];
  }
  if (tid < MT * 2) sh_nbr[tid >> 1][78 + (tid & 1)] = -1.0f;
  __syncthreads();

  // ---- Phase A2: kp = padded @ gen_W^T + gen_b (float4-vectorized dot) ----
  // channels 0..77 = neighbors, 78..79 = -1 (in sh_nbr), 80..83 folded to bias.
  if (tid < MT * KP * 3) {
    int m = tid / 30, r = tid % 30;
    const float* Wr = gen_W + r * (PAD_H * 3);
    const f32x4* W4 = (const f32x4*)Wr;
    const f32x4* N4 = (const f32x4*)&sh_nbr[m][0];
    f32x4 accv = {0.f, 0.f, 0.f, 0.f};
    #pragma unroll
    for (int j = 0; j < 20; ++j) accv += W4[j] * N4[j];
    sh_kp[m][r] = gen_b[r] - (Wr[80] + Wr[81] + Wr[82] + Wr[83])
                + accv[0] + accv[1] + accv[2] + accv[3];
  }
  __syncthreads();

  // ---- Phase B: w-pairs (h0,h1) per (m,hp,k), packed half2 ----
  for (int p = tid; p < MT * 13 * KP; p += 256) {
    int k = p % KP;
    int t = p / KP;
    int m = t & (MT - 1);
    int hp = t >> 3;
    float kx = sh_kp[m][k * 3 + 0], ky = sh_kp[m][k * 3 + 1], kz = sh_kp[m][k * 3 + 2];
    int h0 = hp * 2;
    float dx0 = sh_nbr[m][h0 * 3 + 0] - kx;
    float dy0 = sh_nbr[m][h0 * 3 + 1] - ky;
    float dz0 = sh_nbr[m][h0 * 3 + 2] - kz;
    float w0 = fmaxf(1.0f - sqrtf(dx0 * dx0 + dy0 * dy0 + dz0 * dz0) * (1.0f / 1.2f), 0.0f);
    float dx1 = sh_nbr[m][h0 * 3 + 3] - kx;
    float dy1 = sh_nbr[m][h0 * 3 + 4] - ky;
    float dz1 = sh_nbr[m][h0 * 3 + 5] - kz;
    float w1 = fmaxf(1.0f - sqrtf(dx1 * dx1 + dy1 * dy1 + dz1 * dz1) * (1.0f / 1.2f), 0.0f);
    sh_aw[m][hp][k] = pkrtz_u32(w0, w1);
  }
  __syncthreads();

  // ---- Phase C: weighted[m][k][i] = sum_h w[m,k,h] * x[ind[m][h]][i] ----
  // 32 threads/point, 2 channels each; v_dot2_f32_f16 over h-pairs;
  // depth-4-row rotating register prefetch; NT stores (don't thrash L2/L3).
  {
    const int m  = tid >> 5;
    const int i0 = (tid & 31) * 2;
    float acc0[KP], acc1[KP];
    #pragma unroll
    for (int k = 0; k < KP; ++k) { acc0[k] = 0.f; acc1[k] = 0.f; }

    unsigned int xr[4];
    #pragma unroll
    for (int h = 0; h < 4; ++h)
      xr[h] = *(const unsigned int*)(xh + (long)sh_ind[m][h] * CIN + i0);

    #pragma unroll
    for (int p = 0; p < 13; ++p) {
      unsigned int r0 = xr[(2 * p) & 3];
      unsigned int r1 = xr[(2 * p + 1) & 3];
      if (2 * p + 4 < NB_H)
        xr[(2 * p) & 3] = *(const unsigned int*)(xh + (long)sh_ind[m][2 * p + 4] * CIN + i0);
      if (2 * p + 5 < NB_H)
        xr[(2 * p + 1) & 3] = *(const unsigned int*)(xh + (long)sh_ind[m][2 * p + 5] * CIN + i0);
      // pair_j = (x_h0[j], x_h1[j]) : v_perm byte shuffles
      unsigned int pair0 = __builtin_amdgcn_perm(r1, r0, 0x05040100u);
      unsigned int pair1 = __builtin_amdgcn_perm(r1, r0, 0x07060302u);
      const unsigned int* wrow = &sh_aw[m][p][0];
      #pragma unroll
      for (int k = 0; k < KP; ++k) {
        unsigned int w2 = wrow[k];
        acc0[k] = fdot2u(w2, pair0, acc0[k]);
        acc1[k] = fdot2u(w2, pair1, acc1[k]);
      }
    }
    #pragma unroll
    for (int k = 0; k < KP; ++k) {
      __builtin_nontemporal_store(
          pkrtz_u32(acc0[k], acc1[k]),
          (unsigned int*)(wg + (long)(base + m) * (KP * CIN) + k * CIN + i0));
    }
  }
}

// ---- kernel B: out[65536][128] = wg[65536][640] @ B[640][128] (fp16 MFMA) ---
// BM=64 rows/block, 4 waves x 2 col-tiles, BK=64 double-buffered LDS A-chunks.
__global__ void __launch_bounds__(256, 4)
kpconv_gemm(const unsigned short* __restrict__ wg,
            const unsigned short* __restrict__ bp,
            float* __restrict__ out) {

  __shared__ unsigned short sA[2][BM][72];   // 2 x 9216 B

  const int tid  = threadIdx.x;
  const int wave = tid >> 6;
  const int lane = tid & 63;
  const long row0 = (long)blockIdx.x * BM;

  const int srow = tid >> 3;        // 0..31
  const int scb  = tid & 7;         // col block 0..7

  // stage chunk 0 (NT loads: wg is stream-once, keep bp L2-resident)
  {
    u16x8 a = __builtin_nontemporal_load((const u16x8*)(wg + (row0 + srow) * 640 + scb * 8));
    u16x8 b = __builtin_nontemporal_load((const u16x8*)(wg + (row0 + srow + 32) * 640 + scb * 8));
    *(u16x8*)&sA[0][srow][scb * 8] = a;
    *(u16x8*)&sA[0][srow + 32][scb * 8] = b;
  }

  f32x4 acc[4][2];
  #pragma unroll
  for (int rt = 0; rt < 4; ++rt)
    #pragma unroll
    for (int c = 0; c < 2; ++c) acc[rt][c] = (f32x4){0.f, 0.f, 0.f, 0.f};

  const int ct0  = wave * 2, ct1 = ct0 + 1;
  const int arow = lane & 15;
  const int aq   = lane >> 4;
  int cur = 0;

  for (int kc = 0; kc < 10; ++kc) {
    __syncthreads();
    u16x8 p0, p1;
    if (kc < 9) {   // prefetch next A-chunk, hidden behind MFMA phase
      p0 = __builtin_nontemporal_load((const u16x8*)(wg + (row0 + srow) * 640 + (kc + 1) * 64 + scb * 8));
      p1 = __builtin_nontemporal_load((const u16x8*)(wg + (row0 + srow + 32) * 640 + (kc + 1) * 64 + scb * 8));
    }
    #pragma unroll
    for (int ks2 = 0; ks2 < 2; ++ks2) {
      int ks = kc * 2 + ks2;
      u16x8 b0u = *(const u16x8*)(bp + (long)((ct0 * 20 + ks) * 64 + lane) * 8);
      u16x8 b1u = *(const u16x8*)(bp + (long)((ct1 * 20 + ks) * 64 + lane) * 8);
      f16x8 b0 = __builtin_bit_cast(f16x8, b0u);
      f16x8 b1 = __builtin_bit_cast(f16x8, b1u);
      #pragma unroll
      for (int rt = 0; rt < 4; ++rt) {
        u16x8 au = *(const u16x8*)&sA[cur][rt * 16 + arow][ks2 * 32 + aq * 8];
        f16x8 a = __builtin_bit_cast(f16x8, au);
        acc[rt][0] = __builtin_amdgcn_mfma_f32_16x16x32_f16(a, b0, acc[rt][0], 0, 0, 0);
        acc[rt][1] = __builtin_amdgcn_mfma_f32_16x16x32_f16(a, b1, acc[rt][1], 0, 0, 0);
      }
    }
    if (kc < 9) {
      *(u16x8*)&sA[1 - cur][srow][scb * 8] = p0;
      *(u16x8*)&sA[1 - cur][srow + 32][scb * 8] = p1;
      cur ^= 1;
    }
  }

  // C/D layout: col = lane&15, row = (lane>>4)*4 + reg  [measured m89/m91]
  const int col   = lane & 15;
  const int rbase = aq * 4;
  #pragma unroll
  for (int rt = 0; rt < 4; ++rt)
    #pragma unroll
    for (int r = 0; r < 4; ++r) {
      long row = row0 + rt * 16 + rbase + r;
      __builtin_nontemporal_store(acc[rt][0][r], &out[row * COUT + ct0 * 16 + col]);
      __builtin_nontemporal_store(acc[rt][1][r], &out[row * COUT + ct1 * 16 + col]);
    }
}

extern "C" void kernel_launch(void* const* d_in, const int* in_sizes, int n_in,
                              void* d_out, int out_size, void* d_ws, size_t ws_size,
                              hipStream_t stream) {
  const float* q_pts = (const float*)d_in[0];
  const float* s_pts = (const float*)d_in[1];
  const float* x     = (const float*)d_in[2];
  const float* gen_W = (const float*)d_in[3];
  const float* gen_b = (const float*)d_in[4];
  const float* wts   = (const float*)d_in[5];
  const int*   inds  = (const int*)d_in[6];
  float* out = (float*)d_out;

  unsigned short* xh = (unsigned short*)d_ws;            // (N_S+1)*CIN fp16 = 8.39 MB
  unsigned short* bp = xh + (size_t)(N_S + 1) * CIN;     // 81920 fp16 = 160 KB
  unsigned short* wg = bp + (size_t)81920;               // N_Q*640 fp16 = 83.9 MB

  prep_kernel<<<CVT_BLOCKS + PACK_BLOCKS, 256, 0, stream>>>(x, wts, xh, bp);
  kpconv_gather<<<N_Q / MT, 256, 0, stream>>>(q_pts, s_pts, gen_W, gen_b,
                                              inds, xh, wg);
  kpconv_gemm<<<N_Q / BM, 256, 0, stream>>>(wg, bp, out);
}